// Round 3
// baseline (3013.942 us; speedup 1.0000x reference)
//
#include <hip/hip_runtime.h>
#include <math.h>

#define NB 32
#define L  1024
#define CH 256                 // timesteps per chunk
#define NCH (L / CH)           // 4 chunks
#define RC (NB * CH)           // 8192 rows per chunk
#define DM 256
#define DI 512
#define DS 16

// Layout note: all per-chunk activations use (t_local, b, feat) ordering:
// row r = t_local*32 + b.  Row-wise ops (GEMM, LN, dt, conv-pointwise) don't
// care; conv/scan/mean handle time explicitly.

// ---------------------------------------------------------------------------
// p1 (K=4) + bias + LayerNorm for one chunk. Block = one local row.
// ---------------------------------------------------------------------------
__global__ __launch_bounds__(256) void k_p1_ln(
    const float* __restrict__ xseq, const float* __restrict__ w,
    const float* __restrict__ bias, const float* __restrict__ g,
    const float* __restrict__ bb, float* __restrict__ out, int t0)
{
    int r  = blockIdx.x;              // local row
    int b  = r & 31;
    int tl = r >> 5;
    int m  = threadIdx.x;
    const float* xr = xseq + ((size_t)b * L + t0 + tl) * 4;
    float x0 = xr[0], x1 = xr[1], x2 = xr[2], x3 = xr[3];
    const float* wr = w + m * 4;
    float v = bias[m] + x0 * wr[0] + x1 * wr[1] + x2 * wr[2] + x3 * wr[3];

    __shared__ float s1[4], s2[4];
    float a = v, bq = v * v;
    for (int o = 32; o > 0; o >>= 1) { a += __shfl_down(a, o); bq += __shfl_down(bq, o); }
    int wid = m >> 6, lane = m & 63;
    if (lane == 0) { s1[wid] = a; s2[wid] = bq; }
    __syncthreads();
    if (m == 0) {
        s1[0] = s1[0] + s1[1] + s1[2] + s1[3];
        s2[0] = s2[0] + s2[1] + s2[2] + s2[3];
    }
    __syncthreads();
    float mu  = s1[0] * (1.f / 256.f);
    float var = s2[0] * (1.f / 256.f) - mu * mu;
    out[(size_t)r * 256 + m] = (v - mu) * rsqrtf(var + 1e-5f) * g[m] + bb[m];
}

// ---------------------------------------------------------------------------
// standalone LayerNorm over 256 (local rows)
// ---------------------------------------------------------------------------
__global__ __launch_bounds__(256) void k_ln(
    const float* __restrict__ in, const float* __restrict__ g,
    const float* __restrict__ bb, float* __restrict__ out)
{
    int r = blockIdx.x;
    int m = threadIdx.x;
    float v = in[(size_t)r * 256 + m];

    __shared__ float s1[4], s2[4];
    float a = v, bq = v * v;
    for (int o = 32; o > 0; o >>= 1) { a += __shfl_down(a, o); bq += __shfl_down(bq, o); }
    int wid = m >> 6, lane = m & 63;
    if (lane == 0) { s1[wid] = a; s2[wid] = bq; }
    __syncthreads();
    if (m == 0) {
        s1[0] = s1[0] + s1[1] + s1[2] + s1[3];
        s2[0] = s2[0] + s2[1] + s2[2] + s2[3];
    }
    __syncthreads();
    float mu  = s1[0] * (1.f / 256.f);
    float var = s2[0] * (1.f / 256.f) - mu * mu;
    out[(size_t)r * 256 + m] = (v - mu) * rsqrtf(var + 1e-5f) * g[m] + bb[m];
}

// ---------------------------------------------------------------------------
// fp32 tiled GEMM: C[M,N] = A[M,K] * W[N,K]^T (+bias)
// BM=BN=64, BK=16, 256 threads, 4x4/thread. M%64==0, K%16==0, N%4==0.
// ---------------------------------------------------------------------------
template <bool BIAS>
__global__ __launch_bounds__(256) void k_gemm(
    const float* __restrict__ A, const float* __restrict__ W,
    const float* __restrict__ bias, float* __restrict__ C,
    int M, int N, int K)
{
    const int BM = 64, BN = 64, BK = 16;
    __shared__ float As[BK][BM];
    __shared__ float Ws[BK][BN];

    int m0  = blockIdx.x * BM;
    int n0  = blockIdx.y * BN;
    int tid = threadIdx.x;
    int tx  = tid & 15, ty = tid >> 4;
    int lr  = tid >> 2;            // 0..63
    int lc  = (tid & 3) * 4;       // 0,4,8,12

    float acc[4][4] = {};

    for (int k0 = 0; k0 < K; k0 += BK) {
        float4 av = *(const float4*)(A + (size_t)(m0 + lr) * K + k0 + lc);
        As[lc + 0][lr] = av.x; As[lc + 1][lr] = av.y;
        As[lc + 2][lr] = av.z; As[lc + 3][lr] = av.w;
        float4 wv = make_float4(0.f, 0.f, 0.f, 0.f);
        if (n0 + lr < N) wv = *(const float4*)(W + (size_t)(n0 + lr) * K + k0 + lc);
        Ws[lc + 0][lr] = wv.x; Ws[lc + 1][lr] = wv.y;
        Ws[lc + 2][lr] = wv.z; Ws[lc + 3][lr] = wv.w;
        __syncthreads();
#pragma unroll
        for (int k = 0; k < BK; k++) {
            float a[4], bv[4];
            *(float4*)a  = *(const float4*)&As[k][ty * 4];
            *(float4*)bv = *(const float4*)&Ws[k][tx * 4];
#pragma unroll
            for (int i = 0; i < 4; i++)
#pragma unroll
                for (int j = 0; j < 4; j++)
                    acc[i][j] = fmaf(a[i], bv[j], acc[i][j]);
        }
        __syncthreads();
    }

    int n = n0 + tx * 4;
    float4 bv = make_float4(0.f, 0.f, 0.f, 0.f);
    if (BIAS && n < N) bv = *(const float4*)(bias + n);
#pragma unroll
    for (int i = 0; i < 4; i++) {
        if (n < N) {
            float4 v = make_float4(acc[i][0] + bv.x, acc[i][1] + bv.y,
                                   acc[i][2] + bv.z, acc[i][3] + bv.w);
            *(float4*)(C + (size_t)(m0 + ty * 4 + i) * N + n) = v;
        }
    }
}

// ---------------------------------------------------------------------------
// depthwise causal conv1d (k=4) + SiLU, chunked with halo.
// halo holds xi for global timesteps t0-3..t0-1, layout [3][32][512].
// ---------------------------------------------------------------------------
__global__ __launch_bounds__(256) void k_conv(
    const float* __restrict__ xz, const float* __restrict__ halo,
    const float* __restrict__ cw, const float* __restrict__ cb,
    float* __restrict__ xc, int t0)
{
    size_t idx = (size_t)blockIdx.x * 256 + threadIdx.x;   // over RC*512
    int d  = (int)(idx & (DI - 1));
    int r  = (int)(idx >> 9);     // local row
    int b  = r & 31;
    int tl = r >> 5;

    float4 wv = *(const float4*)(cw + d * 4);
    float wk[4] = { wv.x, wv.y, wv.z, wv.w };
    float acc = cb[d];

    if (tl >= 3) {
        const float* base = xz + ((size_t)(tl - 3) * 32 + b) * 1024 + d;
#pragma unroll
        for (int k = 0; k < 4; k++) acc = fmaf(wk[k], base[(size_t)k * 32 * 1024], acc);
    } else {
#pragma unroll
        for (int k = 0; k < 4; k++) {
            int ts = t0 + tl - 3 + k;          // global source timestep
            float v;
            if (ts < 0) continue;
            else if (ts >= t0) v = xz[((size_t)(ts - t0) * 32 + b) * 1024 + d];
            else v = halo[((size_t)(ts - t0 + 3) * 32 + b) * 512 + d];
            acc = fmaf(wk[k], v, acc);
        }
    }
    xc[idx] = acc / (1.f + __expf(-acc));      // silu
}

// save last 3 timesteps' xi into halo for the next chunk
__global__ __launch_bounds__(256) void k_halo(
    const float* __restrict__ xz, float* __restrict__ halo)
{
    int idx = blockIdx.x * 256 + threadIdx.x;  // over 3*32*512
    int d = idx & 511;
    int b = (idx >> 9) & 31;
    int s = idx >> 14;                         // 0..2
    halo[idx] = xz[(((size_t)(CH - 3 + s) * 32 + b) << 10) + d];
}

// ---------------------------------------------------------------------------
// dt projection (K=16) + softplus
// ---------------------------------------------------------------------------
__global__ __launch_bounds__(256) void k_dt(
    const float* __restrict__ dbc, const float* __restrict__ dtw,
    const float* __restrict__ dtb, float* __restrict__ dtf)
{
    size_t idx = (size_t)blockIdx.x * 256 + threadIdx.x;   // over RC*512
    int d = (int)(idx & (DI - 1));
    size_t r = idx >> 9;
    const float* dr = dbc + r * 48;
    const float* w  = dtw + d * 16;
    float s = dtb[d];
#pragma unroll
    for (int k = 0; k < 16; k++) s = fmaf(dr[k], w[k], s);
    dtf[idx] = (s > 20.f) ? s : log1pf(expf(s));
}

// ---------------------------------------------------------------------------
// selective scan over one chunk; h carried in hs ([b*512+d]*16).
// Fused epilogue y=(y+xc*D)*silu(z) written in-place over dtf.
// ---------------------------------------------------------------------------
__global__ __launch_bounds__(256) void k_scan(
    float* __restrict__ dtf, const float* __restrict__ xc,
    const float* __restrict__ dbc, const float* __restrict__ xz,
    const float* __restrict__ A_log, const float* __restrict__ Dp,
    float* __restrict__ hs, int first)
{
    int b = blockIdx.x >> 1;
    int d = ((blockIdx.x & 1) << 8) + threadIdx.x;

    float A[DS], h[DS];
    float* hp = hs + ((size_t)(b << 9) + d) * DS;
#pragma unroll
    for (int s = 0; s < DS; s++) {
        A[s] = -expf(A_log[d * DS + s]);
        h[s] = first ? 0.f : hp[s];
    }
    float Dv = Dp[d];

    __shared__ float BC[16][32];

    for (int t0l = 0; t0l < CH; t0l += 16) {
        for (int f = threadIdx.x; f < 512; f += 256) {
            int tt = f >> 5, j = f & 31;
            BC[tt][j] = dbc[((size_t)(t0l + tt) * 32 + b) * 48 + 16 + j];
        }
        __syncthreads();
        for (int tt = 0; tt < 16; tt++) {
            int tl = t0l + tt;
            size_t row = (size_t)tl * 32 + b;
            size_t idx = row * DI + d;
            float dt = dtf[idx];
            float x  = xc[idx];
            float z  = xz[(row << 10) + DI + d];
            float dtx = dt * x;
            float y = 0.f;
#pragma unroll
            for (int s = 0; s < DS; s++) {
                float dA = __expf(dt * A[s]);
                h[s] = fmaf(dA, h[s], dtx * BC[tt][s]);
                y = fmaf(h[s], BC[tt][16 + s], y);
            }
            dtf[idx] = (y + x * Dv) * (z / (1.f + __expf(-z)));
        }
        __syncthreads();
    }
#pragma unroll
    for (int s = 0; s < DS; s++) hp[s] = h[s];
}

// ---------------------------------------------------------------------------
// accumulate sum over this chunk's timesteps into meanacc[b][m]
// ---------------------------------------------------------------------------
__global__ __launch_bounds__(256) void k_meanacc(
    const float* __restrict__ mo, float* __restrict__ meanacc, int first)
{
    int b = blockIdx.x;
    int m = threadIdx.x;
    float s = 0.f;
    for (int tl = 0; tl < CH; tl++)
        s += mo[((size_t)tl * 32 + b) * 256 + m];
    if (first) meanacc[b * 256 + m] = s;
    else       meanacc[b * 256 + m] += s;
}

// ---------------------------------------------------------------------------
// head: elu(h1) then h2 dot, one block per batch
// ---------------------------------------------------------------------------
__global__ __launch_bounds__(128) void k_head(
    const float* __restrict__ meanacc, const float* __restrict__ xst,
    const float* __restrict__ h1w, const float* __restrict__ h1b,
    const float* __restrict__ h2w, const float* __restrict__ h2b,
    float* __restrict__ out)
{
    int b = blockIdx.x;
    int j = threadIdx.x;
    const float* wr = h1w + j * 261;
    const float* mr = meanacc + b * 256;
    float s = h1b[j];
    for (int k = 0; k < 256; k++) s = fmaf(mr[k] * (1.f / 1024.f), wr[k], s);
    for (int k = 0; k < 5; k++) s = fmaf(xst[b * 5 + k], wr[256 + k], s);
    float e = (s > 0.f) ? s : expm1f(s);

    __shared__ float sb[128];
    sb[j] = e * h2w[j];
    __syncthreads();
    for (int o = 64; o > 0; o >>= 1) {
        if (j < o) sb[j] += sb[j + o];
        __syncthreads();
    }
    if (j == 0) out[b] = sb[0] + h2b[0];
}

// ---------------------------------------------------------------------------
// host side: streaming chunks
// ---------------------------------------------------------------------------
static void run_mamba_chunk(hipStream_t stream, const float* xin, void* const* P,
                            float* xzc, float* xcc, float* dbcc, float* dtc,
                            float* moc, float* halo, float* hstate, int t0)
{
    const float* in_w   = (const float*)P[0];
    const float* cw     = (const float*)P[1];
    const float* cb     = (const float*)P[2];
    const float* xpw    = (const float*)P[3];
    const float* dtw    = (const float*)P[4];
    const float* dtbias = (const float*)P[5];
    const float* Alog   = (const float*)P[6];
    const float* Dp     = (const float*)P[7];
    const float* ow     = (const float*)P[8];
    int first = (t0 == 0);

    k_gemm<false><<<dim3(RC / 64, 1024 / 64), 256, 0, stream>>>(
        xin, in_w, nullptr, xzc, RC, 1024, 256);
    k_conv<<<RC * DI / 256, 256, 0, stream>>>(xzc, halo, cw, cb, xcc, t0);
    k_halo<<<3 * 32 * 512 / 256, 256, 0, stream>>>(xzc, halo);
    k_gemm<false><<<dim3(RC / 64, 1), 256, 0, stream>>>(
        xcc, xpw, nullptr, dbcc, RC, 48, 512);
    k_dt<<<RC * DI / 256, 256, 0, stream>>>(dbcc, dtw, dtbias, dtc);
    k_scan<<<NB * 2, 256, 0, stream>>>(dtc, xcc, dbcc, xzc, Alog, Dp, hstate, first);
    k_gemm<false><<<dim3(RC / 64, 256 / 64), 256, 0, stream>>>(
        dtc, ow, nullptr, moc, RC, 256, 512);
}

extern "C" void kernel_launch(void* const* d_in, const int* in_sizes, int n_in,
                              void* d_out, int out_size, void* d_ws, size_t ws_size,
                              hipStream_t stream)
{
    const float* xseq = (const float*)d_in[0];
    const float* xst  = (const float*)d_in[1];
    const float* p1w  = (const float*)d_in[2];
    const float* p1b  = (const float*)d_in[3];
    const float* ln1g = (const float*)d_in[4];
    const float* ln1b = (const float*)d_in[5];
    const float* p2w  = (const float*)d_in[6];
    const float* p2b  = (const float*)d_in[7];
    const float* ln2g = (const float*)d_in[8];
    const float* ln2b = (const float*)d_in[9];
    const float* h1w  = (const float*)d_in[10];
    const float* h1b  = (const float*)d_in[11];
    const float* h2w  = (const float*)d_in[12];
    const float* h2b  = (const float*)d_in[13];

    float* ws    = (float*)d_ws;
    float* xzc   = ws;                               // RC*1024  (8.39M f)
    float* xcc   = xzc  + (size_t)RC * 1024;         // RC*512
    float* dtc   = xcc  + (size_t)RC * 512;          // RC*512
    float* dbcc  = dtc  + (size_t)RC * 512;          // RC*48
    float* x1c   = dbcc + (size_t)RC * 48;           // RC*256
    float* moc   = x1c  + (size_t)RC * 256;          // RC*256
    float* halo1 = moc  + (size_t)RC * 256;          // 3*32*512
    float* halo2 = halo1 + 3 * 32 * 512;             // 3*32*512
    float* hs1   = halo2 + 3 * 32 * 512;             // 32*512*16
    float* hs2   = hs1  + 32 * 512 * DS;             // 32*512*16
    float* macc  = hs2  + 32 * 512 * DS;             // 32*256
    size_t need  = (size_t)(macc + 32 * 256 - ws) * sizeof(float);
    if (ws_size < need) return;   // tripwire: fail validation cleanly, don't fault

    for (int c = 0; c < NCH; c++) {
        int t0 = c * CH;
        int first = (c == 0);

        // p1 + LN1 for this chunk
        k_p1_ln<<<RC, 256, 0, stream>>>(xseq, p1w, p1b, ln1g, ln1b, x1c, t0);

        // mamba 1 (params d_in[14..22])
        run_mamba_chunk(stream, x1c, d_in + 14, xzc, xcc, dbcc, dtc, moc,
                        halo1, hs1, t0);

        // p2 + LN2 (tmp in xzc, free after scan)
        k_gemm<true><<<dim3(RC / 64, 256 / 64), 256, 0, stream>>>(
            moc, p2w, p2b, xzc, RC, 256, 256);
        k_ln<<<RC, 256, 0, stream>>>(xzc, ln2g, ln2b, x1c);

        // mamba 2 (params d_in[23..31])
        run_mamba_chunk(stream, x1c, d_in + 23, xzc, xcc, dbcc, dtc, moc,
                        halo2, hs2, t0);

        // accumulate mean over this chunk
        k_meanacc<<<NB, 256, 0, stream>>>(moc, macc, first);
    }

    k_head<<<NB, 128, 0, stream>>>(macc, xst, h1w, h1b, h2w, h2b, (float*)d_out);
}

// Round 4
// 2061.460 us; speedup vs baseline: 1.4620x; 1.4620x over previous
//
#include <hip/hip_runtime.h>
#include <math.h>

#define NB 32
#define L  1024
#define CH 256                 // timesteps per chunk
#define NCH (L / CH)           // 4 chunks
#define RC (NB * CH)           // 8192 rows per chunk
#define DM 256
#define DI 512
#define DS 16
#define SCT 32                 // sub-chunk timesteps (scan pass A)
#define NSC (CH / SCT)         // 8 sub-chunks

// Layout: per-chunk activations use (t_local, b, feat): row r = t_local*32 + b.

// ---------------------------------------------------------------------------
// p1 (K=4) + bias + LayerNorm for one chunk. Block = one local row.
// ---------------------------------------------------------------------------
__global__ __launch_bounds__(256) void k_p1_ln(
    const float* __restrict__ xseq, const float* __restrict__ w,
    const float* __restrict__ bias, const float* __restrict__ g,
    const float* __restrict__ bb, float* __restrict__ out, int t0)
{
    int r  = blockIdx.x;
    int b  = r & 31;
    int tl = r >> 5;
    int m  = threadIdx.x;
    const float* xr = xseq + ((size_t)b * L + t0 + tl) * 4;
    float x0 = xr[0], x1 = xr[1], x2 = xr[2], x3 = xr[3];
    const float* wr = w + m * 4;
    float v = bias[m] + x0 * wr[0] + x1 * wr[1] + x2 * wr[2] + x3 * wr[3];

    __shared__ float s1[4], s2[4];
    float a = v, bq = v * v;
    for (int o = 32; o > 0; o >>= 1) { a += __shfl_down(a, o); bq += __shfl_down(bq, o); }
    int wid = m >> 6, lane = m & 63;
    if (lane == 0) { s1[wid] = a; s2[wid] = bq; }
    __syncthreads();
    if (m == 0) {
        s1[0] = s1[0] + s1[1] + s1[2] + s1[3];
        s2[0] = s2[0] + s2[1] + s2[2] + s2[3];
    }
    __syncthreads();
    float mu  = s1[0] * (1.f / 256.f);
    float var = s2[0] * (1.f / 256.f) - mu * mu;
    out[(size_t)r * 256 + m] = (v - mu) * rsqrtf(var + 1e-5f) * g[m] + bb[m];
}

// ---------------------------------------------------------------------------
// standalone LayerNorm over 256 (local rows)
// ---------------------------------------------------------------------------
__global__ __launch_bounds__(256) void k_ln(
    const float* __restrict__ in, const float* __restrict__ g,
    const float* __restrict__ bb, float* __restrict__ out)
{
    int r = blockIdx.x;
    int m = threadIdx.x;
    float v = in[(size_t)r * 256 + m];

    __shared__ float s1[4], s2[4];
    float a = v, bq = v * v;
    for (int o = 32; o > 0; o >>= 1) { a += __shfl_down(a, o); bq += __shfl_down(bq, o); }
    int wid = m >> 6, lane = m & 63;
    if (lane == 0) { s1[wid] = a; s2[wid] = bq; }
    __syncthreads();
    if (m == 0) {
        s1[0] = s1[0] + s1[1] + s1[2] + s1[3];
        s2[0] = s2[0] + s2[1] + s2[2] + s2[3];
    }
    __syncthreads();
    float mu  = s1[0] * (1.f / 256.f);
    float var = s2[0] * (1.f / 256.f) - mu * mu;
    out[(size_t)r * 256 + m] = (v - mu) * rsqrtf(var + 1e-5f) * g[m] + bb[m];
}

// ---------------------------------------------------------------------------
// fp32 tiled GEMM (odd shapes, e.g. N=48): BM=BN=64, BK=16, 4x4/thread.
// ---------------------------------------------------------------------------
template <bool BIAS>
__global__ __launch_bounds__(256) void k_gemm(
    const float* __restrict__ A, const float* __restrict__ W,
    const float* __restrict__ bias, float* __restrict__ C,
    int M, int N, int K)
{
    const int BM = 64, BN = 64, BK = 16;
    __shared__ float As[BK][BM];
    __shared__ float Ws[BK][BN];

    int m0  = blockIdx.x * BM;
    int n0  = blockIdx.y * BN;
    int tid = threadIdx.x;
    int tx  = tid & 15, ty = tid >> 4;
    int lr  = tid >> 2;
    int lc  = (tid & 3) * 4;

    float acc[4][4] = {};

    for (int k0 = 0; k0 < K; k0 += BK) {
        float4 av = *(const float4*)(A + (size_t)(m0 + lr) * K + k0 + lc);
        As[lc + 0][lr] = av.x; As[lc + 1][lr] = av.y;
        As[lc + 2][lr] = av.z; As[lc + 3][lr] = av.w;
        float4 wv = make_float4(0.f, 0.f, 0.f, 0.f);
        if (n0 + lr < N) wv = *(const float4*)(W + (size_t)(n0 + lr) * K + k0 + lc);
        Ws[lc + 0][lr] = wv.x; Ws[lc + 1][lr] = wv.y;
        Ws[lc + 2][lr] = wv.z; Ws[lc + 3][lr] = wv.w;
        __syncthreads();
#pragma unroll
        for (int k = 0; k < BK; k++) {
            float a[4], bv[4];
            *(float4*)a  = *(const float4*)&As[k][ty * 4];
            *(float4*)bv = *(const float4*)&Ws[k][tx * 4];
#pragma unroll
            for (int i = 0; i < 4; i++)
#pragma unroll
                for (int j = 0; j < 4; j++)
                    acc[i][j] = fmaf(a[i], bv[j], acc[i][j]);
        }
        __syncthreads();
    }

    int n = n0 + tx * 4;
    float4 bv = make_float4(0.f, 0.f, 0.f, 0.f);
    if (BIAS && n < N) bv = *(const float4*)(bias + n);
#pragma unroll
    for (int i = 0; i < 4; i++) {
        if (n < N) {
            float4 v = make_float4(acc[i][0] + bv.x, acc[i][1] + bv.y,
                                   acc[i][2] + bv.z, acc[i][3] + bv.w);
            *(float4*)(C + (size_t)(m0 + ty * 4 + i) * N + n) = v;
        }
    }
}

// ---------------------------------------------------------------------------
// fp32 tiled GEMM, main shapes: BM=128, BN=64, BK=16, 8x4/thread.
// Requires M%128==0, N%64==0, K%16==0.
// ---------------------------------------------------------------------------
template <bool BIAS>
__global__ __launch_bounds__(256) void k_gemm2(
    const float* __restrict__ A, const float* __restrict__ W,
    const float* __restrict__ bias, float* __restrict__ C,
    int M, int N, int K)
{
    const int BM = 128, BN = 64, BK = 16;
    __shared__ float As[BK][BM];
    __shared__ float Ws[BK][BN];
    int m0 = blockIdx.x * BM, n0 = blockIdx.y * BN;
    int tid = threadIdx.x;
    int tx = tid & 15, ty = tid >> 4;
    int ar = tid >> 1, ac = (tid & 1) * 8;
    int wr = tid >> 2, wc = (tid & 3) * 4;

    float acc[8][4] = {};

    for (int k0 = 0; k0 < K; k0 += BK) {
        float4 a0 = *(const float4*)(A + (size_t)(m0 + ar) * K + k0 + ac);
        float4 a1 = *(const float4*)(A + (size_t)(m0 + ar) * K + k0 + ac + 4);
        As[ac + 0][ar] = a0.x; As[ac + 1][ar] = a0.y;
        As[ac + 2][ar] = a0.z; As[ac + 3][ar] = a0.w;
        As[ac + 4][ar] = a1.x; As[ac + 5][ar] = a1.y;
        As[ac + 6][ar] = a1.z; As[ac + 7][ar] = a1.w;
        float4 w0 = *(const float4*)(W + (size_t)(n0 + wr) * K + k0 + wc);
        Ws[wc + 0][wr] = w0.x; Ws[wc + 1][wr] = w0.y;
        Ws[wc + 2][wr] = w0.z; Ws[wc + 3][wr] = w0.w;
        __syncthreads();
#pragma unroll
        for (int k = 0; k < BK; k++) {
            float a[8], bv[4];
            *(float4*)&a[0] = *(const float4*)&As[k][ty * 8];
            *(float4*)&a[4] = *(const float4*)&As[k][ty * 8 + 4];
            *(float4*)bv    = *(const float4*)&Ws[k][tx * 4];
#pragma unroll
            for (int i = 0; i < 8; i++)
#pragma unroll
                for (int j = 0; j < 4; j++)
                    acc[i][j] = fmaf(a[i], bv[j], acc[i][j]);
        }
        __syncthreads();
    }

    int n = n0 + tx * 4;
    float4 bv = make_float4(0.f, 0.f, 0.f, 0.f);
    if (BIAS) bv = *(const float4*)(bias + n);
#pragma unroll
    for (int i = 0; i < 8; i++) {
        float4 v = make_float4(acc[i][0] + bv.x, acc[i][1] + bv.y,
                               acc[i][2] + bv.z, acc[i][3] + bv.w);
        *(float4*)(C + (size_t)(m0 + ty * 8 + i) * N + n) = v;
    }
}

// ---------------------------------------------------------------------------
// depthwise causal conv1d (k=4) + SiLU, chunked with halo [3][32][512].
// ---------------------------------------------------------------------------
__global__ __launch_bounds__(256) void k_conv(
    const float* __restrict__ xz, const float* __restrict__ halo,
    const float* __restrict__ cw, const float* __restrict__ cb,
    float* __restrict__ xc, int t0)
{
    size_t idx = (size_t)blockIdx.x * 256 + threadIdx.x;   // over RC*512
    int d  = (int)(idx & (DI - 1));
    int r  = (int)(idx >> 9);
    int b  = r & 31;
    int tl = r >> 5;

    float4 wv = *(const float4*)(cw + d * 4);
    float wk[4] = { wv.x, wv.y, wv.z, wv.w };
    float acc = cb[d];

    if (tl >= 3) {
        const float* base = xz + ((size_t)(tl - 3) * 32 + b) * 1024 + d;
#pragma unroll
        for (int k = 0; k < 4; k++) acc = fmaf(wk[k], base[(size_t)k * 32 * 1024], acc);
    } else {
#pragma unroll
        for (int k = 0; k < 4; k++) {
            int ts = t0 + tl - 3 + k;
            float v;
            if (ts < 0) continue;
            else if (ts >= t0) v = xz[((size_t)(ts - t0) * 32 + b) * 1024 + d];
            else v = halo[((size_t)(ts - t0 + 3) * 32 + b) * 512 + d];
            acc = fmaf(wk[k], v, acc);
        }
    }
    xc[idx] = acc / (1.f + __expf(-acc));      // silu
}

__global__ __launch_bounds__(256) void k_halo(
    const float* __restrict__ xz, float* __restrict__ halo)
{
    int idx = blockIdx.x * 256 + threadIdx.x;  // over 3*32*512
    int d = idx & 511;
    int b = (idx >> 9) & 31;
    int s = idx >> 14;
    halo[idx] = xz[(((size_t)(CH - 3 + s) * 32 + b) << 10) + d];
}

// ---------------------------------------------------------------------------
// dt projection (K=16) + softplus
// ---------------------------------------------------------------------------
__global__ __launch_bounds__(256) void k_dt(
    const float* __restrict__ dbc, const float* __restrict__ dtw,
    const float* __restrict__ dtb, float* __restrict__ dtf)
{
    size_t idx = (size_t)blockIdx.x * 256 + threadIdx.x;   // over RC*512
    int d = (int)(idx & (DI - 1));
    size_t r = idx >> 9;
    const float* dr = dbc + r * 48;
    const float* w  = dtw + d * 16;
    float s = dtb[d];
#pragma unroll
    for (int k = 0; k < 16; k++) s = fmaf(dr[k], w[k], s);
    dtf[idx] = (s > 20.f) ? s : log1pf(expf(s));
}

// ---------------------------------------------------------------------------
// scan pass A: local scan per sub-chunk (h=0). Writes raw-y into the dead
// xi half of xz, cumdt in-place over dtf, sub-chunk-final h into hend.
// grid: b(32) x half(2) x subchunk(8) = 512 blocks
// ---------------------------------------------------------------------------
__global__ __launch_bounds__(256) void k_scanA(
    float* __restrict__ dtf, const float* __restrict__ xc,
    const float* __restrict__ dbc, float* __restrict__ xz,
    const float* __restrict__ A_log, float* __restrict__ hend)
{
    int bx = blockIdx.x;
    int b    = bx >> 4;
    int half = (bx >> 3) & 1;
    int c    = bx & 7;
    int d = (half << 8) + threadIdx.x;

    float A[DS], h[DS];
#pragma unroll
    for (int s = 0; s < DS; s++) {
        A[s] = -__expf(A_log[d * DS + s]);
        h[s] = 0.f;
    }

    __shared__ float BC[SCT][32];
    for (int f = threadIdx.x; f < SCT * 32; f += 256) {
        int tt = f >> 5, j = f & 31;
        BC[tt][j] = dbc[((size_t)(c * SCT + tt) * 32 + b) * 48 + 16 + j];
    }
    __syncthreads();

    float cum = 0.f;
    for (int tt = 0; tt < SCT; tt++) {
        size_t row = (size_t)(c * SCT + tt) * 32 + b;
        size_t idx = row * DI + d;
        float dt = dtf[idx];
        cum += dt;
        dtf[idx] = cum;                       // cumdt for passes B/C
        float x = xc[idx];
        float dtx = dt * x;
        float y = 0.f;
#pragma unroll
        for (int s = 0; s < DS; s++) {
            float dA = __expf(dt * A[s]);
            h[s] = fmaf(dA, h[s], dtx * BC[tt][s]);
            y = fmaf(h[s], BC[tt][16 + s], y);
        }
        xz[(row << 10) + d] = y;              // raw y into dead xi half
    }
    float* hp = hend + ((size_t)(c * 32 + b) * 512 + d) * DS;
#pragma unroll
    for (int s = 0; s < DS; s++) hp[s] = h[s];
}

// ---------------------------------------------------------------------------
// scan pass B: carry propagation across the 8 sub-chunks.
// hend[c] is overwritten with h_init[c]; final carry goes to hs.
// grid: 32*512*16/256 = 1024 blocks
// ---------------------------------------------------------------------------
__global__ __launch_bounds__(256) void k_scanB(
    const float* __restrict__ dtf, float* __restrict__ hend,
    const float* __restrict__ A_log, float* __restrict__ hs, int first)
{
    int id = blockIdx.x * 256 + threadIdx.x;
    int s = id & 15;
    int d = (id >> 4) & 511;
    int b = id >> 13;
    float A = -__expf(A_log[d * DS + s]);
    size_t hsi = ((size_t)(b << 9) + d) * DS + s;
    float hin = first ? 0.f : hs[hsi];
    for (int c = 0; c < NSC; c++) {
        size_t hi = ((size_t)(c * 32 + b) * 512 + d) * DS + s;
        float he = hend[hi];
        float cend = dtf[((size_t)(c * SCT + SCT - 1) * 32 + b) * DI + d];
        hend[hi] = hin;                       // now holds h_init[c]
        hin = fmaf(__expf(A * cend), hin, he);
    }
    hs[hsi] = hin;
}

// ---------------------------------------------------------------------------
// scan pass C: y = y_raw + sum_s C[s]*exp(A*cumdt)*h_init[s], then epilogue
// (y + x*D)*silu(z), written over dtf. grid: RC*512/256 = 16384 blocks
// ---------------------------------------------------------------------------
__global__ __launch_bounds__(256) void k_scanC(
    float* __restrict__ dtf, const float* __restrict__ xc,
    const float* __restrict__ dbc, const float* __restrict__ xz,
    const float* __restrict__ A_log, const float* __restrict__ Dp,
    const float* __restrict__ hinit)
{
    size_t idx = (size_t)blockIdx.x * 256 + threadIdx.x;
    int d = (int)(idx & 511);
    size_t r = idx >> 9;
    int b  = (int)(r & 31);
    int tl = (int)(r >> 5);
    int c  = tl / SCT;

    float y   = xz[(r << 10) + d];
    float cum = dtf[idx];
    float x   = xc[idx];
    float z   = xz[(r << 10) + 512 + d];
    const float* hp = hinit + ((size_t)(c * 32 + b) * 512 + d) * DS;
    const float* Cr = dbc + r * 48 + 32;
    const float* Ar = A_log + d * DS;
#pragma unroll
    for (int s = 0; s < DS; s++) {
        float A = -__expf(Ar[s]);
        y = fmaf(Cr[s] * __expf(A * cum), hp[s], y);
    }
    dtf[idx] = (y + x * Dp[d]) * (z / (1.f + __expf(-z)));
}

// ---------------------------------------------------------------------------
// accumulate sum over this chunk's timesteps into meanacc[b][m]
// ---------------------------------------------------------------------------
__global__ __launch_bounds__(256) void k_meanacc(
    const float* __restrict__ mo, float* __restrict__ meanacc, int first)
{
    int b = blockIdx.x;
    int m = threadIdx.x;
    float s = 0.f;
    for (int tl = 0; tl < CH; tl++)
        s += mo[((size_t)tl * 32 + b) * 256 + m];
    if (first) meanacc[b * 256 + m] = s;
    else       meanacc[b * 256 + m] += s;
}

// ---------------------------------------------------------------------------
// head: elu(h1) then h2 dot, one block per batch
// ---------------------------------------------------------------------------
__global__ __launch_bounds__(128) void k_head(
    const float* __restrict__ meanacc, const float* __restrict__ xst,
    const float* __restrict__ h1w, const float* __restrict__ h1b,
    const float* __restrict__ h2w, const float* __restrict__ h2b,
    float* __restrict__ out)
{
    int b = blockIdx.x;
    int j = threadIdx.x;
    const float* wr = h1w + j * 261;
    const float* mr = meanacc + b * 256;
    float s = h1b[j];
    for (int k = 0; k < 256; k++) s = fmaf(mr[k] * (1.f / 1024.f), wr[k], s);
    for (int k = 0; k < 5; k++) s = fmaf(xst[b * 5 + k], wr[256 + k], s);
    float e = (s > 0.f) ? s : expm1f(s);

    __shared__ float sb[128];
    sb[j] = e * h2w[j];
    __syncthreads();
    for (int o = 64; o > 0; o >>= 1) {
        if (j < o) sb[j] += sb[j + o];
        __syncthreads();
    }
    if (j == 0) out[b] = sb[0] + h2b[0];
}

// ---------------------------------------------------------------------------
// host side: streaming chunks
// ---------------------------------------------------------------------------
static void run_mamba_chunk(hipStream_t stream, const float* xin, void* const* P,
                            float* xzc, float* xcc, float* dbcc, float* dtc,
                            float* moc, float* hscratch, float* halo,
                            float* hstate, int t0)
{
    const float* in_w   = (const float*)P[0];
    const float* cw     = (const float*)P[1];
    const float* cb     = (const float*)P[2];
    const float* xpw    = (const float*)P[3];
    const float* dtw    = (const float*)P[4];
    const float* dtbias = (const float*)P[5];
    const float* Alog   = (const float*)P[6];
    const float* Dp     = (const float*)P[7];
    const float* ow     = (const float*)P[8];
    int first = (t0 == 0);

    k_gemm2<false><<<dim3(RC / 128, 1024 / 64), 256, 0, stream>>>(
        xin, in_w, nullptr, xzc, RC, 1024, 256);
    k_conv<<<RC * DI / 256, 256, 0, stream>>>(xzc, halo, cw, cb, xcc, t0);
    k_halo<<<3 * 32 * 512 / 256, 256, 0, stream>>>(xzc, halo);
    k_gemm<false><<<dim3(RC / 64, 1), 256, 0, stream>>>(
        xcc, xpw, nullptr, dbcc, RC, 48, 512);
    k_dt<<<RC * DI / 256, 256, 0, stream>>>(dbcc, dtw, dtbias, dtc);
    k_scanA<<<32 * 2 * NSC, 256, 0, stream>>>(dtc, xcc, dbcc, xzc, Alog, hscratch);
    k_scanB<<<32 * 512 * DS / 256, 256, 0, stream>>>(dtc, hscratch, Alog, hstate, first);
    k_scanC<<<RC * DI / 256, 256, 0, stream>>>(dtc, xcc, dbcc, xzc, Alog, Dp, hscratch);
    k_gemm2<false><<<dim3(RC / 128, 256 / 64), 256, 0, stream>>>(
        dtc, ow, nullptr, moc, RC, 256, 512);
}

extern "C" void kernel_launch(void* const* d_in, const int* in_sizes, int n_in,
                              void* d_out, int out_size, void* d_ws, size_t ws_size,
                              hipStream_t stream)
{
    const float* xseq = (const float*)d_in[0];
    const float* xst  = (const float*)d_in[1];
    const float* p1w  = (const float*)d_in[2];
    const float* p1b  = (const float*)d_in[3];
    const float* ln1g = (const float*)d_in[4];
    const float* ln1b = (const float*)d_in[5];
    const float* p2w  = (const float*)d_in[6];
    const float* p2b  = (const float*)d_in[7];
    const float* ln2g = (const float*)d_in[8];
    const float* ln2b = (const float*)d_in[9];
    const float* h1w  = (const float*)d_in[10];
    const float* h1b  = (const float*)d_in[11];
    const float* h2w  = (const float*)d_in[12];
    const float* h2b  = (const float*)d_in[13];

    float* ws    = (float*)d_ws;
    float* xzc   = ws;                               // RC*1024
    float* xcc   = xzc  + (size_t)RC * 1024;         // RC*512
    float* dtc   = xcc  + (size_t)RC * 512;          // RC*512
    float* dbcc  = dtc  + (size_t)RC * 512;          // RC*48
    float* x1c   = dbcc + (size_t)RC * 48;           // RC*256 (also scan hend scratch)
    float* moc   = x1c  + (size_t)RC * 256;          // RC*256
    float* halo1 = moc  + (size_t)RC * 256;          // 3*32*512
    float* halo2 = halo1 + 3 * 32 * 512;             // 3*32*512
    float* hs1   = halo2 + 3 * 32 * 512;             // 32*512*16
    float* hs2   = hs1  + 32 * 512 * DS;             // 32*512*16
    float* macc  = hs2  + 32 * 512 * DS;             // 32*256
    size_t need  = (size_t)(macc + 32 * 256 - ws) * sizeof(float);
    if (ws_size < need) return;   // tripwire: fail cleanly, don't fault

    for (int c = 0; c < NCH; c++) {
        int t0 = c * CH;
        int first = (c == 0);

        // p1 + LN1 for this chunk
        k_p1_ln<<<RC, 256, 0, stream>>>(xseq, p1w, p1b, ln1g, ln1b, x1c, t0);

        // mamba 1 (params d_in[14..22]); x1c doubles as scan scratch after in_proj
        run_mamba_chunk(stream, x1c, d_in + 14, xzc, xcc, dbcc, dtc, moc,
                        x1c, halo1, hs1, t0);

        // p2 + LN2 (tmp in xzc, dead after scan)
        k_gemm2<true><<<dim3(RC / 128, 256 / 64), 256, 0, stream>>>(
            moc, p2w, p2b, xzc, RC, 256, 256);
        k_ln<<<RC, 256, 0, stream>>>(xzc, ln2g, ln2b, x1c);

        // mamba 2 (params d_in[23..31])
        run_mamba_chunk(stream, x1c, d_in + 23, xzc, xcc, dbcc, dtc, moc,
                        x1c, halo2, hs2, t0);

        // accumulate mean over this chunk
        k_meanacc<<<NB, 256, 0, stream>>>(moc, macc, first);
    }

    k_head<<<NB, 128, 0, stream>>>(macc, xst, h1w, h1b, h2w, h2b, (float*)d_out);
}

// Round 5
// 1648.514 us; speedup vs baseline: 1.8283x; 1.2505x over previous
//
#include <hip/hip_runtime.h>
#include <math.h>

#define NB 32
#define L  1024
#define CH 256                 // timesteps per chunk
#define NCH (L / CH)           // 4 chunks
#define RC (NB * CH)           // 8192 rows per chunk
#define DM 256
#define DI 512
#define DS 16
#define SCT 32                 // sub-chunk timesteps (scan pass A)
#define NSC (CH / SCT)         // 8 sub-chunks

typedef short short8 __attribute__((ext_vector_type(8)));
typedef float f32x4 __attribute__((ext_vector_type(4)));

// bf16 split helpers: x ~= hi + lo, both bf16 (rne). pair = hi | (lo<<16).
__device__ inline unsigned f2bf_u(float x) {
    unsigned u = __float_as_uint(x);
    return (u + 0x7fffu + ((u >> 16) & 1u)) >> 16;
}
__device__ inline unsigned packpair(float v) {
    unsigned h = f2bf_u(v);
    float hf = __uint_as_float(h << 16);
    unsigned l = f2bf_u(v - hf);
    return h | (l << 16);
}

// Layout: per-chunk activations use (t_local, b, feat): row r = t_local*32 + b.

// ---------------------------------------------------------------------------
// p1 (K=4) + bias + LayerNorm; emits bf16 hi/lo pairs for the MFMA in_proj.
// ---------------------------------------------------------------------------
__global__ __launch_bounds__(256) void k_p1_ln(
    const float* __restrict__ xseq, const float* __restrict__ w,
    const float* __restrict__ bias, const float* __restrict__ g,
    const float* __restrict__ bb, unsigned* __restrict__ out, int t0)
{
    int r  = blockIdx.x;
    int b  = r & 31;
    int tl = r >> 5;
    int m  = threadIdx.x;
    const float* xr = xseq + ((size_t)b * L + t0 + tl) * 4;
    float x0 = xr[0], x1 = xr[1], x2 = xr[2], x3 = xr[3];
    const float* wr = w + m * 4;
    float v = bias[m] + x0 * wr[0] + x1 * wr[1] + x2 * wr[2] + x3 * wr[3];

    __shared__ float s1[4], s2[4];
    float a = v, bq = v * v;
    for (int o = 32; o > 0; o >>= 1) { a += __shfl_down(a, o); bq += __shfl_down(bq, o); }
    int wid = m >> 6, lane = m & 63;
    if (lane == 0) { s1[wid] = a; s2[wid] = bq; }
    __syncthreads();
    if (m == 0) {
        s1[0] = s1[0] + s1[1] + s1[2] + s1[3];
        s2[0] = s2[0] + s2[1] + s2[2] + s2[3];
    }
    __syncthreads();
    float mu  = s1[0] * (1.f / 256.f);
    float var = s2[0] * (1.f / 256.f) - mu * mu;
    float o2 = (v - mu) * rsqrtf(var + 1e-5f) * g[m] + bb[m];
    out[(size_t)r * 256 + m] = packpair(o2);
}

// ---------------------------------------------------------------------------
// LayerNorm over 256; fp32 in, bf16-pair out (feeds MFMA in_proj).
// ---------------------------------------------------------------------------
__global__ __launch_bounds__(256) void k_ln(
    const float* __restrict__ in, const float* __restrict__ g,
    const float* __restrict__ bb, unsigned* __restrict__ out)
{
    int r = blockIdx.x;
    int m = threadIdx.x;
    float v = in[(size_t)r * 256 + m];

    __shared__ float s1[4], s2[4];
    float a = v, bq = v * v;
    for (int o = 32; o > 0; o >>= 1) { a += __shfl_down(a, o); bq += __shfl_down(bq, o); }
    int wid = m >> 6, lane = m & 63;
    if (lane == 0) { s1[wid] = a; s2[wid] = bq; }
    __syncthreads();
    if (m == 0) {
        s1[0] = s1[0] + s1[1] + s1[2] + s1[3];
        s2[0] = s2[0] + s2[1] + s2[2] + s2[3];
    }
    __syncthreads();
    float mu  = s1[0] * (1.f / 256.f);
    float var = s2[0] * (1.f / 256.f) - mu * mu;
    float o2 = (v - mu) * rsqrtf(var + 1e-5f) * g[m] + bb[m];
    out[(size_t)r * 256 + m] = packpair(o2);
}

// ---------------------------------------------------------------------------
// weight fp32 -> bf16 hi/lo pair
// ---------------------------------------------------------------------------
__global__ __launch_bounds__(256) void k_wcvt(
    const float* __restrict__ w, unsigned* __restrict__ o, int n)
{
    int i = blockIdx.x * 256 + threadIdx.x;
    if (i < n) o[i] = packpair(w[i]);
}

// ---------------------------------------------------------------------------
// split-bf16 MFMA GEMM: C[M,N] = A[M,K] * W[N,K]^T (+bias), 3-term split.
// A, W are bf16 hi/lo pair arrays (uint per elem). 128x128 tile, BK=32,
// 4 waves, each computing a 64x64 quadrant of 4x4 16x16x32 frags.
// OUTK: 0 = fp32 out, 1 = pair out. Requires M%128==0, N%128==0, K%32==0.
// ---------------------------------------------------------------------------
template <int OUTK, bool BIAS>
__global__ __launch_bounds__(256) void k_gmfma(
    const unsigned* __restrict__ Ap, int lda,
    const unsigned* __restrict__ Wp,
    const float* __restrict__ bias, void* __restrict__ Cv,
    int N, int K)
{
    // pitch 40 bf16 (80 B): 16B-aligned rows, conflict-free frag reads
    __shared__ unsigned short Ah[128 * 40], Al[128 * 40];
    __shared__ unsigned short Wh[128 * 40], Wl[128 * 40];

    int tid = threadIdx.x;
    int wv = tid >> 6, ln = tid & 63;
    int wr = wv >> 1, wc = wv & 1;           // wave quadrant in 2x2
    int m0 = blockIdx.x * 128, n0 = blockIdx.y * 128;
    int sr = tid >> 1, sk = (tid & 1) << 4;  // staging: row, k-offset (16 elems)
    int frow = ln & 15, fk = (ln >> 4) << 3; // frag: row-in-16, k-offset

    f32x4 acc[4][4] = {};

    for (int k0 = 0; k0 < K; k0 += 32) {
        const unsigned* ap = Ap + (size_t)(m0 + sr) * lda + k0 + sk;
        const unsigned* wp = Wp + (size_t)(n0 + sr) * K + k0 + sk;
        uint4 qa[4], qw[4];
#pragma unroll
        for (int i = 0; i < 4; i++) qa[i] = *(const uint4*)(ap + i * 4);
#pragma unroll
        for (int i = 0; i < 4; i++) qw[i] = *(const uint4*)(wp + i * 4);

        __syncthreads();   // previous iteration's frag reads done

        unsigned short th[16], tl[16];
#pragma unroll
        for (int i = 0; i < 4; i++) {
            th[i*4+0] = (unsigned short)qa[i].x; tl[i*4+0] = (unsigned short)(qa[i].x >> 16);
            th[i*4+1] = (unsigned short)qa[i].y; tl[i*4+1] = (unsigned short)(qa[i].y >> 16);
            th[i*4+2] = (unsigned short)qa[i].z; tl[i*4+2] = (unsigned short)(qa[i].z >> 16);
            th[i*4+3] = (unsigned short)qa[i].w; tl[i*4+3] = (unsigned short)(qa[i].w >> 16);
        }
        *(short8*)&Ah[sr * 40 + sk]     = *(short8*)&th[0];
        *(short8*)&Ah[sr * 40 + sk + 8] = *(short8*)&th[8];
        *(short8*)&Al[sr * 40 + sk]     = *(short8*)&tl[0];
        *(short8*)&Al[sr * 40 + sk + 8] = *(short8*)&tl[8];
#pragma unroll
        for (int i = 0; i < 4; i++) {
            th[i*4+0] = (unsigned short)qw[i].x; tl[i*4+0] = (unsigned short)(qw[i].x >> 16);
            th[i*4+1] = (unsigned short)qw[i].y; tl[i*4+1] = (unsigned short)(qw[i].y >> 16);
            th[i*4+2] = (unsigned short)qw[i].z; tl[i*4+2] = (unsigned short)(qw[i].z >> 16);
            th[i*4+3] = (unsigned short)qw[i].w; tl[i*4+3] = (unsigned short)(qw[i].w >> 16);
        }
        *(short8*)&Wh[sr * 40 + sk]     = *(short8*)&th[0];
        *(short8*)&Wh[sr * 40 + sk + 8] = *(short8*)&th[8];
        *(short8*)&Wl[sr * 40 + sk]     = *(short8*)&tl[0];
        *(short8*)&Wl[sr * 40 + sk + 8] = *(short8*)&tl[8];

        __syncthreads();

        short8 afh[4], afl[4], wfh[4], wfl[4];
#pragma unroll
        for (int g = 0; g < 4; g++) {
            int ra = (wr * 64 + g * 16 + frow) * 40 + fk;
            int rw = (wc * 64 + g * 16 + frow) * 40 + fk;
            afh[g] = *(const short8*)&Ah[ra];
            afl[g] = *(const short8*)&Al[ra];
            wfh[g] = *(const short8*)&Wh[rw];
            wfl[g] = *(const short8*)&Wl[rw];
        }
#pragma unroll
        for (int mg = 0; mg < 4; mg++)
#pragma unroll
            for (int ng = 0; ng < 4; ng++) {
                acc[mg][ng] = __builtin_amdgcn_mfma_f32_16x16x32_bf16(afh[mg], wfh[ng], acc[mg][ng], 0, 0, 0);
                acc[mg][ng] = __builtin_amdgcn_mfma_f32_16x16x32_bf16(afh[mg], wfl[ng], acc[mg][ng], 0, 0, 0);
                acc[mg][ng] = __builtin_amdgcn_mfma_f32_16x16x32_bf16(afl[mg], wfh[ng], acc[mg][ng], 0, 0, 0);
            }
    }

    // epilogue: C layout col=lane&15, row=(lane>>4)*4+reg  [verified m89]
#pragma unroll
    for (int ng = 0; ng < 4; ng++) {
        int col = n0 + wc * 64 + ng * 16 + frow;
        float bv = BIAS ? bias[col] : 0.f;
#pragma unroll
        for (int mg = 0; mg < 4; mg++)
#pragma unroll
            for (int r = 0; r < 4; r++) {
                int row = m0 + wr * 64 + mg * 16 + (ln >> 4) * 4 + r;
                float v = acc[mg][ng][r] + bv;
                if (OUTK == 0) ((float*)Cv)[(size_t)row * N + col] = v;
                else           ((unsigned*)Cv)[(size_t)row * N + col] = packpair(v);
            }
    }
}

// ---------------------------------------------------------------------------
// fp32 tiled GEMM (xproj, N=48): BM=BN=64, BK=16, 4x4/thread.
// ---------------------------------------------------------------------------
template <bool BIAS>
__global__ __launch_bounds__(256) void k_gemm(
    const float* __restrict__ A, const float* __restrict__ W,
    const float* __restrict__ bias, float* __restrict__ C,
    int M, int N, int K)
{
    const int BM = 64, BN = 64, BK = 16;
    __shared__ float As[BK][BM];
    __shared__ float Ws[BK][BN];

    int m0  = blockIdx.x * BM;
    int n0  = blockIdx.y * BN;
    int tid = threadIdx.x;
    int tx  = tid & 15, ty = tid >> 4;
    int lr  = tid >> 2;
    int lc  = (tid & 3) * 4;

    float acc[4][4] = {};

    for (int k0 = 0; k0 < K; k0 += BK) {
        float4 av = *(const float4*)(A + (size_t)(m0 + lr) * K + k0 + lc);
        As[lc + 0][lr] = av.x; As[lc + 1][lr] = av.y;
        As[lc + 2][lr] = av.z; As[lc + 3][lr] = av.w;
        float4 wv = make_float4(0.f, 0.f, 0.f, 0.f);
        if (n0 + lr < N) wv = *(const float4*)(W + (size_t)(n0 + lr) * K + k0 + lc);
        Ws[lc + 0][lr] = wv.x; Ws[lc + 1][lr] = wv.y;
        Ws[lc + 2][lr] = wv.z; Ws[lc + 3][lr] = wv.w;
        __syncthreads();
#pragma unroll
        for (int k = 0; k < BK; k++) {
            float a[4], bv[4];
            *(float4*)a  = *(const float4*)&As[k][ty * 4];
            *(float4*)bv = *(const float4*)&Ws[k][tx * 4];
#pragma unroll
            for (int i = 0; i < 4; i++)
#pragma unroll
                for (int j = 0; j < 4; j++)
                    acc[i][j] = fmaf(a[i], bv[j], acc[i][j]);
        }
        __syncthreads();
    }

    int n = n0 + tx * 4;
    float4 bv = make_float4(0.f, 0.f, 0.f, 0.f);
    if (BIAS && n < N) bv = *(const float4*)(bias + n);
#pragma unroll
    for (int i = 0; i < 4; i++) {
        if (n < N) {
            float4 v = make_float4(acc[i][0] + bv.x, acc[i][1] + bv.y,
                                   acc[i][2] + bv.z, acc[i][3] + bv.w);
            *(float4*)(C + (size_t)(m0 + ty * 4 + i) * N + n) = v;
        }
    }
}

// ---------------------------------------------------------------------------
// depthwise causal conv1d (k=4) + SiLU, chunked with halo [3][32][512].
// ---------------------------------------------------------------------------
__global__ __launch_bounds__(256) void k_conv(
    const float* __restrict__ xz, const float* __restrict__ halo,
    const float* __restrict__ cw, const float* __restrict__ cb,
    float* __restrict__ xc, int t0)
{
    size_t idx = (size_t)blockIdx.x * 256 + threadIdx.x;   // over RC*512
    int d  = (int)(idx & (DI - 1));
    int r  = (int)(idx >> 9);
    int b  = r & 31;
    int tl = r >> 5;

    float4 wv = *(const float4*)(cw + d * 4);
    float wk[4] = { wv.x, wv.y, wv.z, wv.w };
    float acc = cb[d];

    if (tl >= 3) {
        const float* base = xz + ((size_t)(tl - 3) * 32 + b) * 1024 + d;
#pragma unroll
        for (int k = 0; k < 4; k++) acc = fmaf(wk[k], base[(size_t)k * 32 * 1024], acc);
    } else {
#pragma unroll
        for (int k = 0; k < 4; k++) {
            int ts = t0 + tl - 3 + k;
            float v;
            if (ts < 0) continue;
            else if (ts >= t0) v = xz[((size_t)(ts - t0) * 32 + b) * 1024 + d];
            else v = halo[((size_t)(ts - t0 + 3) * 32 + b) * 512 + d];
            acc = fmaf(wk[k], v, acc);
        }
    }
    xc[idx] = acc / (1.f + __expf(-acc));      // silu
}

__global__ __launch_bounds__(256) void k_halo(
    const float* __restrict__ xz, float* __restrict__ halo)
{
    int idx = blockIdx.x * 256 + threadIdx.x;  // over 3*32*512
    int d = idx & 511;
    int b = (idx >> 9) & 31;
    int s = idx >> 14;
    halo[idx] = xz[(((size_t)(CH - 3 + s) * 32 + b) << 10) + d];
}

// ---------------------------------------------------------------------------
// dt projection (K=16) + softplus
// ---------------------------------------------------------------------------
__global__ __launch_bounds__(256) void k_dt(
    const float* __restrict__ dbc, const float* __restrict__ dtw,
    const float* __restrict__ dtb, float* __restrict__ dtf)
{
    size_t idx = (size_t)blockIdx.x * 256 + threadIdx.x;   // over RC*512
    int d = (int)(idx & (DI - 1));
    size_t r = idx >> 9;
    const float* dr = dbc + r * 48;
    const float* w  = dtw + d * 16;
    float s = dtb[d];
#pragma unroll
    for (int k = 0; k < 16; k++) s = fmaf(dr[k], w[k], s);
    dtf[idx] = (s > 20.f) ? s : log1pf(expf(s));
}

// ---------------------------------------------------------------------------
// scan pass A: local scan per sub-chunk (h=0). Raw-y into dead xi half of xz
// (fp32), cumdt in-place over dtf, sub-chunk-final h into hend.
// ---------------------------------------------------------------------------
__global__ __launch_bounds__(256) void k_scanA(
    float* __restrict__ dtf, const float* __restrict__ xc,
    const float* __restrict__ dbc, float* __restrict__ xz,
    const float* __restrict__ A_log, float* __restrict__ hend)
{
    int bx = blockIdx.x;
    int b    = bx >> 4;
    int half = (bx >> 3) & 1;
    int c    = bx & 7;
    int d = (half << 8) + threadIdx.x;

    float A[DS], h[DS];
#pragma unroll
    for (int s = 0; s < DS; s++) {
        A[s] = -__expf(A_log[d * DS + s]);
        h[s] = 0.f;
    }

    __shared__ float BC[SCT][32];
    for (int f = threadIdx.x; f < SCT * 32; f += 256) {
        int tt = f >> 5, j = f & 31;
        BC[tt][j] = dbc[((size_t)(c * SCT + tt) * 32 + b) * 48 + 16 + j];
    }
    __syncthreads();

    float cum = 0.f;
    for (int tt = 0; tt < SCT; tt++) {
        size_t row = (size_t)(c * SCT + tt) * 32 + b;
        size_t idx = row * DI + d;
        float dt = dtf[idx];
        cum += dt;
        dtf[idx] = cum;
        float x = xc[idx];
        float dtx = dt * x;
        float y = 0.f;
#pragma unroll
        for (int s = 0; s < DS; s++) {
            float dA = __expf(dt * A[s]);
            h[s] = fmaf(dA, h[s], dtx * BC[tt][s]);
            y = fmaf(h[s], BC[tt][16 + s], y);
        }
        xz[(row << 10) + d] = y;
    }
    float* hp = hend + ((size_t)(c * 32 + b) * 512 + d) * DS;
#pragma unroll
    for (int s = 0; s < DS; s++) hp[s] = h[s];
}

// ---------------------------------------------------------------------------
// scan pass B: carry propagation across the 8 sub-chunks.
// ---------------------------------------------------------------------------
__global__ __launch_bounds__(256) void k_scanB(
    const float* __restrict__ dtf, float* __restrict__ hend,
    const float* __restrict__ A_log, float* __restrict__ hs, int first)
{
    int id = blockIdx.x * 256 + threadIdx.x;
    int s = id & 15;
    int d = (id >> 4) & 511;
    int b = id >> 13;
    float A = -__expf(A_log[d * DS + s]);
    size_t hsi = ((size_t)(b << 9) + d) * DS + s;
    float hin = first ? 0.f : hs[hsi];
    for (int c = 0; c < NSC; c++) {
        size_t hi = ((size_t)(c * 32 + b) * 512 + d) * DS + s;
        float he = hend[hi];
        float cend = dtf[((size_t)(c * SCT + SCT - 1) * 32 + b) * DI + d];
        hend[hi] = hin;
        hin = fmaf(__expf(A * cend), hin, he);
    }
    hs[hsi] = hin;
}

// ---------------------------------------------------------------------------
// scan pass C: y = y_raw + sum_s C[s]*exp(A*cumdt)*h_init[s], epilogue
// (y + x*D)*silu(z), emitted as bf16 PAIR in-place over xz's xi slot
// (same-thread same-address -> race-free). Feeds MFMA out_proj (lda=1024).
// ---------------------------------------------------------------------------
__global__ __launch_bounds__(256) void k_scanC(
    const float* __restrict__ dtf, const float* __restrict__ xc,
    const float* __restrict__ dbc, float* __restrict__ xz,
    const float* __restrict__ A_log, const float* __restrict__ Dp,
    const float* __restrict__ hinit)
{
    size_t idx = (size_t)blockIdx.x * 256 + threadIdx.x;
    int d = (int)(idx & 511);
    size_t r = idx >> 9;
    int b  = (int)(r & 31);
    int tl = (int)(r >> 5);
    int c  = tl / SCT;

    float y   = xz[(r << 10) + d];
    float cum = dtf[idx];
    float x   = xc[idx];
    float z   = xz[(r << 10) + 512 + d];
    const float* hp = hinit + ((size_t)(c * 32 + b) * 512 + d) * DS;
    const float* Cr = dbc + r * 48 + 32;
    const float* Ar = A_log + d * DS;
#pragma unroll
    for (int s = 0; s < DS; s++) {
        float A = -__expf(Ar[s]);
        y = fmaf(Cr[s] * __expf(A * cum), hp[s], y);
    }
    float yact = (y + x * Dp[d]) * (z / (1.f + __expf(-z)));
    ((unsigned*)xz)[(r << 10) + d] = packpair(yact);
}

// ---------------------------------------------------------------------------
// accumulate sum over this chunk's timesteps into meanacc[b][m]
// ---------------------------------------------------------------------------
__global__ __launch_bounds__(256) void k_meanacc(
    const float* __restrict__ mo, float* __restrict__ meanacc, int first)
{
    int b = blockIdx.x;
    int m = threadIdx.x;
    float s = 0.f;
    for (int tl = 0; tl < CH; tl++)
        s += mo[((size_t)tl * 32 + b) * 256 + m];
    if (first) meanacc[b * 256 + m] = s;
    else       meanacc[b * 256 + m] += s;
}

// ---------------------------------------------------------------------------
// head: elu(h1) then h2 dot, one block per batch
// ---------------------------------------------------------------------------
__global__ __launch_bounds__(128) void k_head(
    const float* __restrict__ meanacc, const float* __restrict__ xst,
    const float* __restrict__ h1w, const float* __restrict__ h1b,
    const float* __restrict__ h2w, const float* __restrict__ h2b,
    float* __restrict__ out)
{
    int b = blockIdx.x;
    int j = threadIdx.x;
    const float* wr = h1w + j * 261;
    const float* mr = meanacc + b * 256;
    float s = h1b[j];
    for (int k = 0; k < 256; k++) s = fmaf(mr[k] * (1.f / 1024.f), wr[k], s);
    for (int k = 0; k < 5; k++) s = fmaf(xst[b * 5 + k], wr[256 + k], s);
    float e = (s > 0.f) ? s : expm1f(s);

    __shared__ float sb[128];
    sb[j] = e * h2w[j];
    __syncthreads();
    for (int o = 64; o > 0; o >>= 1) {
        if (j < o) sb[j] += sb[j + o];
        __syncthreads();
    }
    if (j == 0) out[b] = sb[0] + h2b[0];
}

// ---------------------------------------------------------------------------
// host side
// ---------------------------------------------------------------------------
static void run_mamba_chunk(hipStream_t stream, const unsigned* xinp, void* const* P,
                            const unsigned* winp, const unsigned* woutp, int out_pairs,
                            float* xzc, float* xcc, float* dbcc, float* dtc,
                            float* moc, float* hsc, float* halo,
                            float* hstate, int t0)
{
    const float* cw     = (const float*)P[1];
    const float* cb     = (const float*)P[2];
    const float* xpw    = (const float*)P[3];
    const float* dtw    = (const float*)P[4];
    const float* dtbias = (const float*)P[5];
    const float* Alog   = (const float*)P[6];
    const float* Dp     = (const float*)P[7];
    int first = (t0 == 0);

    k_gmfma<0, false><<<dim3(RC / 128, 1024 / 128), 256, 0, stream>>>(
        xinp, 256, winp, nullptr, xzc, 1024, 256);
    k_conv<<<RC * DI / 256, 256, 0, stream>>>(xzc, halo, cw, cb, xcc, t0);
    k_halo<<<3 * 32 * 512 / 256, 256, 0, stream>>>(xzc, halo);
    k_gemm<false><<<dim3(RC / 64, 1), 256, 0, stream>>>(
        xcc, xpw, nullptr, dbcc, RC, 48, 512);
    k_dt<<<RC * DI / 256, 256, 0, stream>>>(dbcc, dtw, dtbias, dtc);
    k_scanA<<<32 * 2 * NSC, 256, 0, stream>>>(dtc, xcc, dbcc, xzc, Alog, hsc);
    k_scanB<<<32 * 512 * DS / 256, 256, 0, stream>>>(dtc, hsc, Alog, hstate, first);
    k_scanC<<<RC * DI / 256, 256, 0, stream>>>(dtc, xcc, dbcc, xzc, Alog, Dp, hsc);
    if (out_pairs)
        k_gmfma<1, false><<<dim3(RC / 128, 256 / 128), 256, 0, stream>>>(
            (const unsigned*)xzc, 1024, woutp, nullptr, moc, 256, 512);
    else
        k_gmfma<0, false><<<dim3(RC / 128, 256 / 128), 256, 0, stream>>>(
            (const unsigned*)xzc, 1024, woutp, nullptr, moc, 256, 512);
}

extern "C" void kernel_launch(void* const* d_in, const int* in_sizes, int n_in,
                              void* d_out, int out_size, void* d_ws, size_t ws_size,
                              hipStream_t stream)
{
    const float* xseq = (const float*)d_in[0];
    const float* xst  = (const float*)d_in[1];
    const float* p1w  = (const float*)d_in[2];
    const float* p1b  = (const float*)d_in[3];
    const float* ln1g = (const float*)d_in[4];
    const float* ln1b = (const float*)d_in[5];
    const float* p2w  = (const float*)d_in[6];
    const float* p2b  = (const float*)d_in[7];
    const float* ln2g = (const float*)d_in[8];
    const float* ln2b = (const float*)d_in[9];
    const float* h1w  = (const float*)d_in[10];
    const float* h1b  = (const float*)d_in[11];
    const float* h2w  = (const float*)d_in[12];
    const float* h2b  = (const float*)d_in[13];

    float* ws    = (float*)d_ws;
    float*    xzc   = ws;                                  // RC*1024 f32 (xi half -> pairs after scanC)
    float*    xcc   = xzc  + (size_t)RC * 1024;            // RC*512
    float*    dtc   = xcc  + (size_t)RC * 512;             // RC*512 (dt -> cumdt)
    float*    dbcc  = dtc  + (size_t)RC * 512;             // RC*48
    float*    hsc   = dbcc + (size_t)RC * 48;              // RC*256 scan hend scratch
    float*    moc   = hsc  + (size_t)RC * 256;             // RC*256 (f32 or pairs)
    unsigned* x1p   = (unsigned*)(moc + (size_t)RC * 256); // RC*256 pairs
    float*    halo1 = (float*)(x1p + (size_t)RC * 256);    // 3*32*512
    float*    halo2 = halo1 + 3 * 32 * 512;
    float*    hs1   = halo2 + 3 * 32 * 512;                // 32*512*16
    float*    hs2   = hs1  + 32 * 512 * DS;
    float*    macc  = hs2  + 32 * 512 * DS;                // 32*256
    unsigned* wm1i  = (unsigned*)(macc + 32 * 256);        // 1024*256
    unsigned* wm1o  = wm1i + 262144;                       // 256*512
    unsigned* wm2i  = wm1o + 131072;
    unsigned* wm2o  = wm2i + 262144;
    unsigned* wp2   = wm2o + 131072;                       // 256*256
    size_t need = (size_t)((float*)(wp2 + 65536) - ws) * sizeof(float);
    if (ws_size < need) return;   // tripwire: fail cleanly, don't fault

    // weight bf16-pair conversion (once per launch)
    k_wcvt<<<262144 / 256, 256, 0, stream>>>((const float*)d_in[14], wm1i, 262144);
    k_wcvt<<<131072 / 256, 256, 0, stream>>>((const float*)d_in[22], wm1o, 131072);
    k_wcvt<<<262144 / 256, 256, 0, stream>>>((const float*)d_in[23], wm2i, 262144);
    k_wcvt<<<131072 / 256, 256, 0, stream>>>((const float*)d_in[31], wm2o, 131072);
    k_wcvt<<<65536 / 256, 256, 0, stream>>>(p2w, wp2, 65536);

    for (int c = 0; c < NCH; c++) {
        int t0 = c * CH;
        int first = (c == 0);

        k_p1_ln<<<RC, 256, 0, stream>>>(xseq, p1w, p1b, ln1g, ln1b, x1p, t0);

        // mamba 1 (params d_in[14..22]); out_proj emits pairs for p2
        run_mamba_chunk(stream, x1p, d_in + 14, wm1i, wm1o, 1,
                        xzc, xcc, dbcc, dtc, moc, hsc, halo1, hs1, t0);

        // p2 + LN2 (p2 out into xzc f32 scratch, dead after scanC/out_proj)
        k_gmfma<0, true><<<dim3(RC / 128, 256 / 128), 256, 0, stream>>>(
            (const unsigned*)moc, 256, wp2, p2b, xzc, 256, 256);
        k_ln<<<RC, 256, 0, stream>>>(xzc, ln2g, ln2b, x1p);

        // mamba 2 (params d_in[23..31]); out_proj emits f32 for meanacc
        run_mamba_chunk(stream, x1p, d_in + 23, wm2i, wm2o, 0,
                        xzc, xcc, dbcc, dtc, moc, hsc, halo2, hs2, t0);

        k_meanacc<<<NB, 256, 0, stream>>>(moc, macc, first);
    }

    k_head<<<NB, 128, 0, stream>>>(macc, xst, h1w, h1b, h2w, h2b, (float*)d_out);
}